// Round 3
// baseline (245.071 us; speedup 1.0000x reference)
//
#include <hip/hip_runtime.h>
#include <math.h>

// B=65536, S=64.
// Outputs (concat, f32): L (B,S,3) at offset 0, basis_out (B,S,3,3) at B*S*3.
// HBM: ~192 MiB writes + ~50 MB reads -> ~37 us floor at 6.6 TB/s (the
// measured fillBuffer write ceiling on this box).
//
// Structure: fully wave-parallel, ZERO barriers. Each 64-lane wave owns one
// b (64 samples), stages its own L (768 B) + masked basis (2304 B) in its
// private LDS slice, then sweeps that slice out as dwordx4. Intra-wave
// LDS write->read ordering is hardware-guaranteed (lgkmcnt), so no
// __syncthreads is needed anywhere.

constexpr int S = 64;

__global__ __launch_bounds__(256) void cosine_lobe_kernel(
    const float* __restrict__ viewdir,
    const float* __restrict__ normal,
    const float* __restrict__ r1,
    const void*  __restrict__ ray_mask,   // int32 0/1 or u8 0/1 -- auto-detected
    const float* __restrict__ angs,
    float* __restrict__ out,
    int B)
{
    __shared__ __align__(16) float sL[256 * 3];    // per-wave slices of L
    __shared__ __align__(16) float sBas[256 * 9];  // per-wave slices of basis_out

    const int tid  = threadIdx.x;
    const int gid  = blockIdx.x * 256 + tid;
    const int b    = gid >> 6;         // one b per 64-lane wave
    const int s    = gid & 63;
    const int w    = tid >> 6;         // wave id within block (0..3)
    const int lane = tid & 63;
    const int gw   = blockIdx.x * 4 + w;  // global wave index == b

    // --- detect ray_mask element width (redundant per-thread; 64B L1 hit) ---
    const uint4* mw = (const uint4*)ray_mask;
    const uint4 m0 = mw[0], m1 = mw[1], m2 = mw[2], m3 = mw[3];
    const unsigned acc = m0.x | m0.y | m0.z | m0.w | m1.x | m1.y | m1.z | m1.w |
                         m2.x | m2.y | m2.z | m2.w | m3.x | m3.y | m3.z | m3.w;
    const bool u8mode = acc > 1u;      // byte-packed bools make some word >1

    // --- per-b frame (redundant across the wave; L1-broadcast loads) ---
    const float nx = normal[b * 3 + 0];
    const float ny = normal[b * 3 + 1];
    const float nz = normal[b * 3 + 2];

    float ux, uy, uz;
    if (nz < 0.9f) { ux = 0.0f; uy = 0.0f; uz = 1.0f; }
    else           { ux = -1.0f; uy = 0.0f; uz = 0.0f; }

    // tangent = normalize(cross(up, normal))
    float tx = uy * nz - uz * ny;
    float ty = uz * nx - ux * nz;
    float tz = ux * ny - uy * nx;
    float inv = 1.0f / (sqrtf(tx * tx + ty * ty + tz * tz) + 1e-8f);
    tx *= inv; ty *= inv; tz *= inv;

    // bitangent = normalize(cross(normal, tangent))
    float bx = ny * tz - nz * ty;
    float by = nz * tx - nx * tz;
    float bz = nx * ty - ny * tx;
    inv = 1.0f / (sqrtf(bx * bx + by * by + bz * bz) + 1e-8f);
    bx *= inv; by *= inv; bz *= inv;

    // --- per-(b,s) sample ---
    const float2 a = ((const float2*)angs)[gid];   // coalesced 8B/lane
    float st, ct, sp, cp;
    sincospif(a.x, &st, &ct);                      // theta = u1*pi
    sincospif(2.0f * a.y, &sp, &cp);               // phi   = 2*u2*pi
    const float r = r1[b];
    float hx = r * ct * cp;
    float hy = r * ct * sp;
    float hz = 1.0f - r * st;                      // r*(-sin) + e3.z
    inv = 1.0f / (sqrtf(hx * hx + hy * hy + hz * hz) + 1e-8f);
    hx *= inv; hy *= inv; hz *= inv;
    if (s == 0) { hx = 0.0f; hy = 0.0f; hz = 1.0f; }  // H_l[:,0,:] = e3

    // H = H_l . basis  (einsum bsj,bji->bsi)
    const float Hx = hx * tx + hy * bx + hz * nx;
    const float Hy = hx * ty + hy * by + hz * ny;
    const float Hz = hx * tz + hy * bz + hz * nz;

    const float vx = viewdir[b * 3 + 0];
    const float vy = viewdir[b * 3 + 1];
    const float vz = viewdir[b * 3 + 2];
    const float d2 = 2.0f * (vx * Hx + vy * Hy + vz * Hz);

    float m;
    if (u8mode) m = (float)((const unsigned char*)ray_mask)[gid];
    else        m = (float)((const int*)ray_mask)[gid];

    // --- stage this wave's outputs in its private LDS slice ---
    sL[tid * 3 + 0] = (d2 * Hx - vx) * m;          // stride 3: 2-way alias, free
    sL[tid * 3 + 1] = (d2 * Hy - vy) * m;
    sL[tid * 3 + 2] = (d2 * Hz - vz) * m;

    float* p = &sBas[tid * 9];                     // stride 9: 2-way alias, free
    p[0] = tx * m; p[1] = bx * m; p[2] = nx * m;   // basis_T row-major per s
    p[3] = ty * m; p[4] = by * m; p[5] = ny * m;
    p[6] = tz * m; p[7] = bz * m; p[8] = nz * m;

    // --- wave-private dwordx4 sweep (no barrier: intra-wave lgkmcnt order) ---
    const float4* sL4 = (const float4*)sL;
    const float4* sB4 = (const float4*)sBas;

    // L: wave region = [gw*192, +192) floats = 48 float4
    float4* Lout4 = ((float4*)out) + (size_t)gw * 48;
    if (lane < 48) Lout4[lane] = sL4[w * 48 + lane];

    // basis_out: wave region = [B*S*3 + gw*576, +576) floats = 144 float4
    float4* Bout4 = (float4*)(out + (size_t)B * S * 3) + (size_t)gw * 144;
    Bout4[lane]      = sB4[w * 144 + lane];
    Bout4[64 + lane] = sB4[w * 144 + 64 + lane];
    if (lane < 16) Bout4[128 + lane] = sB4[w * 144 + 128 + lane];
}

extern "C" void kernel_launch(void* const* d_in, const int* in_sizes, int n_in,
                              void* d_out, int out_size, void* d_ws, size_t ws_size,
                              hipStream_t stream) {
    const float* viewdir = (const float*)d_in[0];
    const float* normal  = (const float*)d_in[1];
    const float* r1      = (const float*)d_in[2];
    // d_in[3] = r2 -- unused by the reference computation
    const void*  mask    = d_in[4];
    const float* angs    = (const float*)d_in[5];

    const int B = in_sizes[2];            // 65536
    const int nBlocks = (B * S) / 256;    // 16384

    cosine_lobe_kernel<<<nBlocks, 256, 0, stream>>>(
        viewdir, normal, r1, mask, angs, (float*)d_out, B);
}